// Round 8
// baseline (320.862 us; speedup 1.0000x reference)
//
#include <hip/hip_runtime.h>

typedef unsigned long long ull;
typedef __attribute__((ext_vector_type(8))) short bf16x8;
typedef __attribute__((ext_vector_type(4))) float f32x4;
typedef __attribute__((ext_vector_type(8))) unsigned short u16x8;

#define DECAY 0.99f
#define BETA 0.25f
#define EPSV 1e-5f
#define EPSGAP 0.0625f

// z: [32, 256, 32, 32] fp32 ; embedding: [1024, 256] ; N = 32*32*32 = 32768
#define Dd 256
#define Kk 1024
#define Nn 32768
#define ZELEM 8388608

__device__ __forceinline__ unsigned short f2bf(float f) {
    unsigned int x = __float_as_uint(f);
    x += 0x7FFFu + ((x >> 16) & 1u);          // RNE
    return (unsigned short)(x >> 16);
}
__device__ __forceinline__ float bf2f(unsigned short b) {
    return __uint_as_float(((unsigned int)b) << 16);
}
__device__ __forceinline__ unsigned mono(unsigned b) {
    return b ^ (((int)b >> 31) | 0x80000000u);   // monotone float->uint
}
__device__ __forceinline__ float unmono(unsigned m) {
    unsigned b = (m & 0x80000000u) ? (m ^ 0x80000000u) : ~m;
    return __uint_as_float(b);
}
__device__ __forceinline__ unsigned umin32(unsigned a, unsigned b) { return a < b ? a : b; }
__device__ __forceinline__ unsigned umax32(unsigned a, unsigned b) { return a > b ? a : b; }

// ---------------------------------------------------------------------------
// Kernel 1: pre-split embedding into MFMA-B-fragment order (hi/lo bf16),
// compute esq; zero hist / flagcnt / loss_fix / dw. 64 blocks.
__global__ __launch_bounds__(256) void prep_e_kernel(
        const float* __restrict__ emb, unsigned short* __restrict__ ehg,
        unsigned short* __restrict__ elg, float* __restrict__ esq,
        int* __restrict__ hist, int* __restrict__ flagcnt,
        float* __restrict__ loss_fix, float* __restrict__ dw) {
    const int nsub = blockIdx.x;
    const int t = threadIdx.x;
    if (t < 16) hist[nsub * 16 + t] = 0;
    if (nsub == 0 && t == 16) flagcnt[0] = 0;
    if (nsub == 0 && t == 17) loss_fix[0] = 0.0f;
    {
        float4* dwp = (float4*)dw;
        #pragma unroll
        for (int j = 0; j < 4; ++j)
            dwp[(size_t)(nsub * 256 + t) * 4 + j] = make_float4(0.f, 0.f, 0.f, 0.f);
    }
    #pragma unroll
    for (int it = 0; it < 2; ++it) {
        const int item = it * 256 + t;
        const int kc = item >> 6, lane = item & 63;
        const int quad = lane >> 4, nl = lane & 15;
        const float* ep = emb + (size_t)(nsub * 16 + nl) * Dd + kc * 32 + quad * 8;
        const float4 a = *(const float4*)ep;
        const float4 b4 = *(const float4*)(ep + 4);
        const float v[8] = {a.x, a.y, a.z, a.w, b4.x, b4.y, b4.z, b4.w};
        u16x8 hi, lo;
        #pragma unroll
        for (int j = 0; j < 8; ++j) {
            const unsigned short h = f2bf(v[j]);
            hi[j] = h;
            lo[j] = f2bf(v[j] - bf2f(h));
        }
        const size_t off = ((size_t)(nsub * 8 + kc) * 64 + lane) * 8;
        *(u16x8*)&ehg[off] = hi;
        *(u16x8*)&elg[off] = lo;
    }
    {
        const int nl = t >> 4, seg = t & 15;
        const float* ep = emb + (size_t)(nsub * 16 + nl) * Dd + seg * 16;
        float s = 0.0f;
        #pragma unroll
        for (int j = 0; j < 4; ++j) {
            const float4 v4 = *(const float4*)(ep + j * 4);
            s += v4.x * v4.x + v4.y * v4.y + v4.z * v4.z + v4.w * v4.w;
        }
        #pragma unroll
        for (int d = 1; d < 16; d <<= 1) s += __shfl_xor(s, d);
        if (seg == 0) esq[nsub * 16 + nl] = s;
    }
}

// ---------------------------------------------------------------------------
// Kernel 2: transpose z [32,256,1024] -> zf [32768, 256]. Runs BEFORE dist
// so its 32MB write stream can't evict the e-table during dist's hot loop
// (R6/R7 lesson: fusing this into dist ballooned FETCH 20->243MB).
__global__ __launch_bounds__(256) void transpose_kernel(
        const float* __restrict__ z, float* __restrict__ zf) {
    __shared__ float tile[64][65];
    const int bid = blockIdx.x;
    const int b  = bid >> 6;
    const int ct = (bid >> 4) & 3;
    const int ht = bid & 15;
    const int c0 = ct * 64, hw0 = ht * 64;
    const int t = threadIdx.x;
    const int g  = t & 15;
    const int r0 = t >> 4;
    const size_t zb = (size_t)b * 262144;

    #pragma unroll
    for (int r = 0; r < 4; ++r) {
        const int c_l = r * 16 + r0;
        const float4 v = *(const float4*)(z + zb + (size_t)(c0 + c_l) * 1024 + hw0 + g * 4);
        tile[c_l][g * 4 + 0] = v.x; tile[c_l][g * 4 + 1] = v.y;
        tile[c_l][g * 4 + 2] = v.z; tile[c_l][g * 4 + 3] = v.w;
    }
    __syncthreads();
    #pragma unroll
    for (int r = 0; r < 4; ++r) {
        const int hw_l = r * 16 + r0;
        float4 v;
        v.x = tile[g * 4 + 0][hw_l]; v.y = tile[g * 4 + 1][hw_l];
        v.z = tile[g * 4 + 2][hw_l]; v.w = tile[g * 4 + 3][hw_l];
        *(float4*)(zf + ((size_t)b * 1024 + hw0 + hw_l) * 256 + c0 + g * 4) = v;
    }
}

// ---------------------------------------------------------------------------
// Kernel 3: MFMA distance + top-2 argmin + hist + loss. 512 blocks x
// 64 points x all 1024 codes; 3-pass bf16 error-corrected GEMM.
// No zf write here (un-fused) -> e-table stays L2-resident.
__global__ __launch_bounds__(256, 2) void dist_kernel(
        const float* __restrict__ z, const unsigned short* __restrict__ ehg,
        const unsigned short* __restrict__ elg, const float* __restrict__ esq,
        int* __restrict__ idx_i, float* __restrict__ idx_f,
        int* __restrict__ hist, int* __restrict__ flagcnt,
        int* __restrict__ flaglist, float* __restrict__ flagval,
        float* __restrict__ loss_p) {
    __shared__ __align__(16) unsigned short zh[64 * 256];   // 32KB
    __shared__ __align__(16) unsigned short zl[64 * 256];   // 32KB
    __shared__ ull mb[4][64], ms[4][64];                    // 4KB
    __shared__ float zsqp[256];                             // 1KB

    const int t = threadIdx.x, w = t >> 6, L = t & 63;
    const int quad = L >> 4, lr = L & 15;
    const int m0 = blockIdx.x * 64;
    const int b = m0 >> 10, hw0 = m0 & 1023;

    // ---- stage: wave w converts channels w*64..+63 for all 64 points
    {
        const int c0 = w * 64;
        const float* zp = z + (size_t)b * 262144 + hw0 + L;
        float s = 0.0f;
        #pragma unroll
        for (int cg = 0; cg < 8; ++cg) {
            float v[8];
            #pragma unroll
            for (int j = 0; j < 8; ++j)
                v[j] = zp[(size_t)(c0 + cg * 8 + j) * 1024];
            u16x8 hi, lo;
            #pragma unroll
            for (int j = 0; j < 8; ++j) {
                s = fmaf(v[j], v[j], s);
                const unsigned short h = f2bf(v[j]);
                hi[j] = h;
                lo[j] = f2bf(v[j] - bf2f(h));
            }
            const int chunk = ((c0 >> 3) + cg) ^ (L & 7);
            *(u16x8*)&zh[L * 256 + chunk * 8] = hi;
            *(u16x8*)&zl[L * 256 + chunk * 8] = lo;
        }
        zsqp[L * 4 + w] = s;
    }
    __syncthreads();

    const unsigned short* ehw = ehg + (size_t)(w * 1024 + L) * 8;
    const unsigned short* elw = elg + (size_t)(w * 1024 + L) * 8;

    unsigned bb[16], ss[16];
    #pragma unroll
    for (int i = 0; i < 16; ++i) { bb[i] = 0xFFFFFFFFu; ss[i] = 0xFFFFFFFFu; }

    bf16x8 Bh[2][2], Bl[2][2];
    #pragma unroll
    for (int ni = 0; ni < 2; ++ni) {
        Bh[0][ni] = *(const bf16x8*)(ehw + (size_t)ni * 4096);
        Bl[0][ni] = *(const bf16x8*)(elw + (size_t)ni * 4096);
    }

    for (int nt = 0; nt < 8; ++nt) {
        f32x4 acc[4][2];
        #pragma unroll
        for (int mi = 0; mi < 4; ++mi)
            #pragma unroll
            for (int ni = 0; ni < 2; ++ni) acc[mi][ni] = (f32x4){0.f, 0.f, 0.f, 0.f};

        #pragma unroll
        for (int kc = 0; kc < 8; ++kc) {
            const int cur = kc & 1, nxt = cur ^ 1;
            const int nkc = (kc + 1) & 7;
            const int nnt = (kc == 7) ? ((nt + 1) & 7) : nt;
            #pragma unroll
            for (int ni = 0; ni < 2; ++ni) {
                const size_t o = (size_t)nnt * 32768 + (size_t)ni * 4096 + (size_t)nkc * 512;
                Bh[nxt][ni] = *(const bf16x8*)(ehw + o);
                Bl[nxt][ni] = *(const bf16x8*)(elw + o);
            }
            bf16x8 ah[4], al[4];
            #pragma unroll
            for (int mi = 0; mi < 4; ++mi) {
                const int chunk = (kc * 4 + quad) ^ (lr & 7);
                const int o = (mi * 16 + lr) * 256 + chunk * 8;
                ah[mi] = *(const bf16x8*)&zh[o];
                al[mi] = *(const bf16x8*)&zl[o];
            }
            #pragma unroll
            for (int mi = 0; mi < 4; ++mi)
                #pragma unroll
                for (int ni = 0; ni < 2; ++ni) {
                    acc[mi][ni] = __builtin_amdgcn_mfma_f32_16x16x32_bf16(ah[mi], Bh[cur][ni], acc[mi][ni], 0, 0, 0);
                    acc[mi][ni] = __builtin_amdgcn_mfma_f32_16x16x32_bf16(ah[mi], Bl[cur][ni], acc[mi][ni], 0, 0, 0);
                    acc[mi][ni] = __builtin_amdgcn_mfma_f32_16x16x32_bf16(al[mi], Bh[cur][ni], acc[mi][ni], 0, 0, 0);
                }
        }
        const int q0 = nt * 8 + w * 2;
        const float e0b = esq[q0 * 16 + lr] + 512.0f;
        const float e1b = esq[(q0 + 1) * 16 + lr] + 512.0f;
        #pragma unroll
        for (int mi = 0; mi < 4; ++mi)
            #pragma unroll
            for (int reg = 0; reg < 4; ++reg) {
                const int i = mi * 4 + reg;
                #pragma unroll
                for (int ni = 0; ni < 2; ++ni) {
                    const float val = fmaf(-2.0f, acc[mi][ni][reg], ni ? e1b : e0b);
                    const unsigned pk = (__float_as_uint(val) & 0xFFFFFFC0u) | (unsigned)(q0 + ni);
                    const unsigned mx = umax32(bb[i], pk);
                    bb[i] = umin32(bb[i], pk);
                    ss[i] = umin32(ss[i], mx);
                }
            }
    }

    #pragma unroll
    for (int mi = 0; mi < 4; ++mi)
        #pragma unroll
        for (int reg = 0; reg < 4; ++reg) {
            const int i = mi * 4 + reg;
            ull b2 = ((ull)(bb[i] & 0xFFFFFFC0u) << 14) | (ull)((bb[i] & 63u) * 16 + lr);
            ull s2 = ((ull)(ss[i] & 0xFFFFFFC0u) << 14) | (ull)((ss[i] & 63u) * 16 + lr);
            #pragma unroll
            for (int d = 1; d < 16; d <<= 1) {
                const ull ob = __shfl_xor(b2, d);
                const ull os = __shfl_xor(s2, d);
                const ull mx = ob < b2 ? b2 : ob;
                b2 = ob < b2 ? ob : b2;
                const ull ns = os < s2 ? os : s2;
                s2 = mx < ns ? mx : ns;
            }
            if (lr == 0) {
                const int row = mi * 16 + quad * 4 + reg;
                mb[w][row] = b2;
                ms[w][row] = s2;
            }
        }
    __syncthreads();

    if (t < 64) {
        ull b2 = mb[0][t], s2 = ms[0][t];
        #pragma unroll
        for (int ww = 1; ww < 4; ++ww) {
            const ull ob = mb[ww][t], os = ms[ww][t];
            const ull mx = ob < b2 ? b2 : ob;
            b2 = ob < b2 ? ob : b2;
            const ull ns = os < s2 ? os : s2;
            s2 = mx < ns ? mx : ns;
        }
        const int k = (int)(b2 & 16383ull);
        const float v1 = __uint_as_float((unsigned)(b2 >> 14)) - 512.0f;
        const float v2 = __uint_as_float((unsigned)(s2 >> 14)) - 512.0f;
        idx_i[m0 + t] = k;
        idx_f[m0 + t] = (float)k;
        atomicAdd(&hist[k], 1);
        if (v2 - v1 < EPSGAP) {
            const int pos = atomicAdd(flagcnt, 1);
            flaglist[pos] = m0 + t;
            flagval[pos] = v1;
        }
        float lp = v1 + zsqp[t * 4] + zsqp[t * 4 + 1] + zsqp[t * 4 + 2] + zsqp[t * 4 + 3];
        #pragma unroll
        for (int d = 32; d > 0; d >>= 1) lp += __shfl_down(lp, d);
        if (t == 0) loss_p[blockIdx.x] = lp;
    }
}

// ---------------------------------------------------------------------------
// Kernel 4: exact fp32 re-argmin for flagged points; patches idx/hist/loss.
__global__ __launch_bounds__(256) void fixup_kernel(
        const float* __restrict__ zf, const float* __restrict__ emb,
        const float* __restrict__ esq, const int* __restrict__ flagcnt,
        const int* __restrict__ flaglist, const float* __restrict__ flagval,
        int* __restrict__ idx_i, float* __restrict__ idx_f,
        int* __restrict__ hist, float* __restrict__ loss_fix) {
    __shared__ float zrow[256];
    __shared__ ull red[256];
    const int t = threadIdx.x;
    const int total = flagcnt[0];
    for (int fi = blockIdx.x; fi < total; fi += 512) {
        const int n = flaglist[fi];
        __syncthreads();
        zrow[t] = zf[(size_t)n * Dd + t];
        __syncthreads();
        ull best = ~0ull;
        #pragma unroll
        for (int kc = 0; kc < 4; ++kc) {
            const int k = t * 4 + kc;
            const float* ep = emb + (size_t)k * Dd;
            float dot = 0.0f;
            #pragma unroll 8
            for (int c4 = 0; c4 < 64; ++c4) {
                const float4 e4 = *(const float4*)(ep + c4 * 4);
                const float4 z4 = *(const float4*)&zrow[c4 * 4];
                dot = fmaf(z4.x, e4.x, dot);
                dot = fmaf(z4.y, e4.y, dot);
                dot = fmaf(z4.z, e4.z, dot);
                dot = fmaf(z4.w, e4.w, dot);
            }
            const float val = esq[k] - 2.0f * dot;
            const ull pk = ((ull)mono(__float_as_uint(val)) << 32) | (unsigned)k;
            if (pk < best) best = pk;
        }
        red[t] = best;
        __syncthreads();
        for (int s = 128; s > 0; s >>= 1) {
            if (t < s) { if (red[t + s] < red[t]) red[t] = red[t + s]; }
            __syncthreads();
        }
        if (t == 0) {
            const int knew = (int)(unsigned)(red[0] & 0xFFFFFFFFull);
            const float vnew = unmono((unsigned)(red[0] >> 32));
            const int kold = idx_i[n];
            if (knew != kold) {
                idx_i[n] = knew;
                idx_f[n] = (float)knew;
                atomicSub(&hist[kold], 1);
                atomicAdd(&hist[knew], 1);
            }
            atomicAdd(loss_fix, vnew - flagval[fi]);
        }
    }
}

// ---------------------------------------------------------------------------
// Kernel 5: exclusive scan of hist -> offsets, cursor. 1 block.
__global__ void scan_kernel(const int* __restrict__ hist,
                            int* __restrict__ offsets,
                            int* __restrict__ cursor) {
    __shared__ int scan[1024];
    const int t = threadIdx.x;
    const int v = hist[t];
    scan[t] = v;
    __syncthreads();
    for (int s = 1; s < 1024; s <<= 1) {
        const int add = (t >= s) ? scan[t - s] : 0;
        __syncthreads();
        scan[t] += add;
        __syncthreads();
    }
    const int excl = scan[t] - v;
    offsets[t] = excl;
    cursor[t] = excl;
}

// ---------------------------------------------------------------------------
// Kernel 6: counting-sort scatter.
__global__ __launch_bounds__(256) void sort_kernel(
        const int* __restrict__ idx, int* __restrict__ cursor,
        int* __restrict__ sorted, int* __restrict__ codes_sorted) {
    const int n = blockIdx.x * 256 + threadIdx.x;
    const int j = idx[n];
    const int pos = atomicAdd(&cursor[j], 1);
    sorted[pos] = n;
    codes_sorted[pos] = j;
}

// ---------------------------------------------------------------------------
// Kernel 7: balanced segmented reduction -> dw (atomic per segment boundary).
__global__ __launch_bounds__(256) void dw_seg_kernel(
        const float* __restrict__ zf, const int* __restrict__ sorted,
        const int* __restrict__ codes_sorted, float* __restrict__ dw) {
    __shared__ int sid[64];
    __shared__ int scode[65];
    const int t = threadIdx.x;
    const int p0 = blockIdx.x * 64;
    if (t < 64) {
        sid[t] = sorted[p0 + t];
        scode[t] = codes_sorted[p0 + t];
    }
    if (t == 64) scode[64] = -1;
    __syncthreads();
    const int c = t;
    float acc = 0.0f;
    #pragma unroll 8
    for (int p = 0; p < 64; ++p) {
        acc += zf[(size_t)sid[p] * Dd + c];
        if (scode[p] != scode[p + 1]) {
            atomicAdd(&dw[(size_t)scode[p] * Dd + c], acc);
            acc = 0.0f;
        }
    }
}

// ---------------------------------------------------------------------------
// Kernel 8: gather z_q (overwrites zf region; runs after fixup/dw_seg).
__global__ __launch_bounds__(256) void gather_kernel(
        const float* __restrict__ emb, const int* __restrict__ idx,
        float* __restrict__ zq_out) {
    const int tid = blockIdx.x * 256 + threadIdx.x;
    const int e0 = tid * 4;
    const int c = (e0 >> 10) & 255;
    const int b = e0 >> 18;
    const int n0 = b * 1024 + (e0 & 1023);
    const int4 j4 = *(const int4*)(idx + n0);
    float4 e;
    e.x = emb[(size_t)j4.x * Dd + c];
    e.y = emb[(size_t)j4.y * Dd + c];
    e.z = emb[(size_t)j4.z * Dd + c];
    e.w = emb[(size_t)j4.w * Dd + c];
    *(float4*)(zq_out + e0) = e;
}

// ---------------------------------------------------------------------------
// Kernel 9: cluster-size EMA + Laplace smoothing + loss reduce. 1 block.
__global__ void finalize1_kernel(const float* __restrict__ ema_cs,
                                 const int* __restrict__ hist,
                                 const float* __restrict__ loss_p,
                                 const float* __restrict__ loss_fix,
                                 float* __restrict__ cs_out,
                                 float* __restrict__ loss_out) {
    __shared__ float red[1024];
    __shared__ float red2[1024];
    const int k = threadIdx.x;
    const float csr = ema_cs[k] * DECAY + (1.0f - DECAY) * (float)hist[k];
    red[k] = csr;
    red2[k] = (k < 512) ? loss_p[k] : 0.0f;
    __syncthreads();
    for (int s = 512; s > 0; s >>= 1) {
        if (k < s) { red[k] += red[k + s]; red2[k] += red2[k + s]; }
        __syncthreads();
    }
    const float nsum = red[0];
    const float cs = (csr + EPSV) / (nsum + (float)Kk * EPSV) * nsum;
    cs_out[k] = cs;
    if (k == 0) loss_out[0] = BETA * (red2[0] + loss_fix[0]) / (float)ZELEM;
}

// ---------------------------------------------------------------------------
// Kernel 10: new_ema_w = EMA(ema_w, dw); new_emb = new_ema_w / cs.
// dw aliases new_emb_out; each thread reads dw[i] then overwrites same i.
__global__ __launch_bounds__(256) void finalize2_kernel(
        const float* __restrict__ ema_w, const float* __restrict__ dw,
        const float* __restrict__ cs_out,
        float* __restrict__ new_emb_out, float* __restrict__ new_ema_w_out) {
    const int i = blockIdx.x * 256 + threadIdx.x;
    const float nw = ema_w[i] * DECAY + (1.0f - DECAY) * dw[i];
    const float cs = cs_out[i >> 8];
    new_ema_w_out[i] = nw;
    new_emb_out[i]   = nw / cs;
}

// ---------------------------------------------------------------------------
extern "C" void kernel_launch(void* const* d_in, const int* in_sizes, int n_in,
                              void* d_out, int out_size, void* d_ws, size_t ws_size,
                              hipStream_t stream) {
    const float* z      = (const float*)d_in[0];
    const float* emb    = (const float*)d_in[1];
    const float* ema_cs = (const float*)d_in[2];
    const float* ema_w  = (const float*)d_in[3];

    float* out = (float*)d_out;
    float* zq_out        = out;                 // 8388608 (zf staging until gather)
    float* idx_out_f     = out + 8388608;       // 32768
    float* loss_out      = out + 8421376;       // 1
    float* new_emb_out   = out + 8421377;       // 262144 (dw staging)
    float* cs_out        = out + 8683521;       // 1024
    float* new_ema_w_out = out + 8684545;       // 262144

    int*   idx_i    = (int*)d_ws;                    // 32768
    int*   sorted   = idx_i + 32768;                 // 32768
    int*   codes_s  = sorted + 32768;                // 32768
    int*   offsets  = codes_s + 32768;               // 1024
    int*   cursor   = offsets + 1024;                // 1024
    int*   hist     = cursor + 1024;                 // 1024
    int*   flagcnt  = hist + 1024;                   // 16
    float* loss_fix = (float*)(flagcnt + 16);        // 16
    int*   flaglist = (int*)(loss_fix + 16);         // 32768
    float* flagval  = (float*)(flaglist + 32768);    // 32768
    float* esq      = flagval + 32768;               // 1024
    float* loss_p   = esq + 1024;                    // 512
    unsigned short* ehg = (unsigned short*)(loss_p + 512);  // 262144 shorts
    unsigned short* elg = ehg + 262144;                     // 262144 shorts

    float* zf = zq_out;        // transposed z staged in zq output region
    float* dw = new_emb_out;   // dw staged in new_embedding output region

    prep_e_kernel<<<64, 256, 0, stream>>>(emb, ehg, elg, esq, hist, flagcnt,
                                          loss_fix, dw);
    transpose_kernel<<<2048, 256, 0, stream>>>(z, zf);
    dist_kernel<<<Nn / 64, 256, 0, stream>>>(z, ehg, elg, esq, idx_i,
                                             idx_out_f, hist, flagcnt,
                                             flaglist, flagval, loss_p);
    fixup_kernel<<<512, 256, 0, stream>>>(zf, emb, esq, flagcnt, flaglist,
                                          flagval, idx_i, idx_out_f, hist,
                                          loss_fix);
    scan_kernel<<<1, 1024, 0, stream>>>(hist, offsets, cursor);
    sort_kernel<<<Nn / 256, 256, 0, stream>>>(idx_i, cursor, sorted, codes_s);
    dw_seg_kernel<<<Nn / 64, 256, 0, stream>>>(zf, sorted, codes_s, dw);
    gather_kernel<<<ZELEM / 1024, 256, 0, stream>>>(emb, idx_i, zq_out);
    finalize1_kernel<<<1, 1024, 0, stream>>>(ema_cs, hist, loss_p, loss_fix,
                                             cs_out, loss_out);
    finalize2_kernel<<<Kk * Dd / 256, 256, 0, stream>>>(ema_w, dw, cs_out,
                                                        new_emb_out, new_ema_w_out);
}

// Round 9
// 300.111 us; speedup vs baseline: 1.0691x; 1.0691x over previous
//
#include <hip/hip_runtime.h>

typedef unsigned long long ull;
typedef __attribute__((ext_vector_type(8))) short bf16x8;
typedef __attribute__((ext_vector_type(4))) float f32x4;
typedef __attribute__((ext_vector_type(8))) unsigned short u16x8;

#define DECAY 0.99f
#define BETA 0.25f
#define EPSV 1e-5f
#define EPSGAP 0.0625f

// z: [32, 256, 32, 32] fp32 ; embedding: [1024, 256] ; N = 32*32*32 = 32768
#define Dd 256
#define Kk 1024
#define Nn 32768
#define ZELEM 8388608

__device__ __forceinline__ unsigned short f2bf(float f) {
    unsigned int x = __float_as_uint(f);
    x += 0x7FFFu + ((x >> 16) & 1u);          // RNE
    return (unsigned short)(x >> 16);
}
__device__ __forceinline__ float bf2f(unsigned short b) {
    return __uint_as_float(((unsigned int)b) << 16);
}
__device__ __forceinline__ unsigned mono(unsigned b) {
    return b ^ (((int)b >> 31) | 0x80000000u);   // monotone float->uint
}
__device__ __forceinline__ float unmono(unsigned m) {
    unsigned b = (m & 0x80000000u) ? (m ^ 0x80000000u) : ~m;
    return __uint_as_float(b);
}
__device__ __forceinline__ unsigned umin32(unsigned a, unsigned b) { return a < b ? a : b; }
__device__ __forceinline__ unsigned umax32(unsigned a, unsigned b) { return a > b ? a : b; }

// ---------------------------------------------------------------------------
// Kernel 1: pre-split embedding into MFMA-B-fragment order (hi/lo bf16),
// compute esq; zero hist / flagcnt / loss_fix / dw. 64 blocks.
__global__ __launch_bounds__(256) void prep_e_kernel(
        const float* __restrict__ emb, unsigned short* __restrict__ ehg,
        unsigned short* __restrict__ elg, float* __restrict__ esq,
        int* __restrict__ hist, int* __restrict__ flagcnt,
        float* __restrict__ loss_fix, float* __restrict__ dw) {
    const int nsub = blockIdx.x;
    const int t = threadIdx.x;
    if (t < 16) hist[nsub * 16 + t] = 0;
    if (nsub == 0 && t == 16) flagcnt[0] = 0;
    if (nsub == 0 && t == 17) loss_fix[0] = 0.0f;
    {
        float4* dwp = (float4*)dw;
        #pragma unroll
        for (int j = 0; j < 4; ++j)
            dwp[(size_t)(nsub * 256 + t) * 4 + j] = make_float4(0.f, 0.f, 0.f, 0.f);
    }
    #pragma unroll
    for (int it = 0; it < 2; ++it) {
        const int item = it * 256 + t;
        const int kc = item >> 6, lane = item & 63;
        const int quad = lane >> 4, nl = lane & 15;
        const float* ep = emb + (size_t)(nsub * 16 + nl) * Dd + kc * 32 + quad * 8;
        const float4 a = *(const float4*)ep;
        const float4 b4 = *(const float4*)(ep + 4);
        const float v[8] = {a.x, a.y, a.z, a.w, b4.x, b4.y, b4.z, b4.w};
        u16x8 hi, lo;
        #pragma unroll
        for (int j = 0; j < 8; ++j) {
            const unsigned short h = f2bf(v[j]);
            hi[j] = h;
            lo[j] = f2bf(v[j] - bf2f(h));
        }
        const size_t off = ((size_t)(nsub * 8 + kc) * 64 + lane) * 8;
        *(u16x8*)&ehg[off] = hi;
        *(u16x8*)&elg[off] = lo;
    }
    {
        const int nl = t >> 4, seg = t & 15;
        const float* ep = emb + (size_t)(nsub * 16 + nl) * Dd + seg * 16;
        float s = 0.0f;
        #pragma unroll
        for (int j = 0; j < 4; ++j) {
            const float4 v4 = *(const float4*)(ep + j * 4);
            s += v4.x * v4.x + v4.y * v4.y + v4.z * v4.z + v4.w * v4.w;
        }
        #pragma unroll
        for (int d = 1; d < 16; d <<= 1) s += __shfl_xor(s, d);
        if (seg == 0) esq[nsub * 16 + nl] = s;
    }
}

// ---------------------------------------------------------------------------
// Kernel 2: transpose z [32,256,1024] -> zf [32768, 256].
__global__ __launch_bounds__(256) void transpose_kernel(
        const float* __restrict__ z, float* __restrict__ zf) {
    __shared__ float tile[64][65];
    const int bid = blockIdx.x;
    const int b  = bid >> 6;
    const int ct = (bid >> 4) & 3;
    const int ht = bid & 15;
    const int c0 = ct * 64, hw0 = ht * 64;
    const int t = threadIdx.x;
    const int g  = t & 15;
    const int r0 = t >> 4;
    const size_t zb = (size_t)b * 262144;

    #pragma unroll
    for (int r = 0; r < 4; ++r) {
        const int c_l = r * 16 + r0;
        const float4 v = *(const float4*)(z + zb + (size_t)(c0 + c_l) * 1024 + hw0 + g * 4);
        tile[c_l][g * 4 + 0] = v.x; tile[c_l][g * 4 + 1] = v.y;
        tile[c_l][g * 4 + 2] = v.z; tile[c_l][g * 4 + 3] = v.w;
    }
    __syncthreads();
    #pragma unroll
    for (int r = 0; r < 4; ++r) {
        const int hw_l = r * 16 + r0;
        float4 v;
        v.x = tile[g * 4 + 0][hw_l]; v.y = tile[g * 4 + 1][hw_l];
        v.z = tile[g * 4 + 2][hw_l]; v.w = tile[g * 4 + 3][hw_l];
        *(float4*)(zf + ((size_t)b * 1024 + hw0 + hw_l) * 256 + c0 + g * 4) = v;
    }
}

// ---------------------------------------------------------------------------
// Kernel 3: MFMA distance + top-2 argmin + hist + loss. 512 blocks x
// 64 points x all 1024 codes; 3-pass bf16 error-corrected GEMM.
// NOTE: plain __launch_bounds__(256) — the (256,2) variant capped VGPRs at
// 128 and spilled the hot loop to scratch (243MB phantom FETCH / 58MB WRITE,
// R6-R8). LDS already caps occupancy at 2 blocks/CU, so the hint was free
// to remove.
__global__ __launch_bounds__(256) void dist_kernel(
        const float* __restrict__ z, const unsigned short* __restrict__ ehg,
        const unsigned short* __restrict__ elg, const float* __restrict__ esq,
        int* __restrict__ idx_i, float* __restrict__ idx_f,
        int* __restrict__ hist, int* __restrict__ flagcnt,
        int* __restrict__ flaglist, float* __restrict__ flagval,
        float* __restrict__ loss_p) {
    __shared__ __align__(16) unsigned short zh[64 * 256];   // 32KB
    __shared__ __align__(16) unsigned short zl[64 * 256];   // 32KB
    __shared__ ull mb[4][64], ms[4][64];                    // 4KB
    __shared__ float zsqp[256];                             // 1KB

    const int t = threadIdx.x, w = t >> 6, L = t & 63;
    const int quad = L >> 4, lr = L & 15;
    const int m0 = blockIdx.x * 64;
    const int b = m0 >> 10, hw0 = m0 & 1023;

    // ---- stage: wave w converts channels w*64..+63 for all 64 points
    {
        const int c0 = w * 64;
        const float* zp = z + (size_t)b * 262144 + hw0 + L;
        float s = 0.0f;
        #pragma unroll
        for (int cg = 0; cg < 8; ++cg) {
            float v[8];
            #pragma unroll
            for (int j = 0; j < 8; ++j)
                v[j] = zp[(size_t)(c0 + cg * 8 + j) * 1024];
            u16x8 hi, lo;
            #pragma unroll
            for (int j = 0; j < 8; ++j) {
                s = fmaf(v[j], v[j], s);
                const unsigned short h = f2bf(v[j]);
                hi[j] = h;
                lo[j] = f2bf(v[j] - bf2f(h));
            }
            const int chunk = ((c0 >> 3) + cg) ^ (L & 7);
            *(u16x8*)&zh[L * 256 + chunk * 8] = hi;
            *(u16x8*)&zl[L * 256 + chunk * 8] = lo;
        }
        zsqp[L * 4 + w] = s;
    }
    __syncthreads();

    const unsigned short* ehw = ehg + (size_t)(w * 1024 + L) * 8;
    const unsigned short* elw = elg + (size_t)(w * 1024 + L) * 8;

    unsigned bb[16], ss[16];
    #pragma unroll
    for (int i = 0; i < 16; ++i) { bb[i] = 0xFFFFFFFFu; ss[i] = 0xFFFFFFFFu; }

    bf16x8 Bh[2][2], Bl[2][2];
    #pragma unroll
    for (int ni = 0; ni < 2; ++ni) {
        Bh[0][ni] = *(const bf16x8*)(ehw + (size_t)ni * 4096);
        Bl[0][ni] = *(const bf16x8*)(elw + (size_t)ni * 4096);
    }

    for (int nt = 0; nt < 8; ++nt) {
        f32x4 acc[4][2];
        #pragma unroll
        for (int mi = 0; mi < 4; ++mi)
            #pragma unroll
            for (int ni = 0; ni < 2; ++ni) acc[mi][ni] = (f32x4){0.f, 0.f, 0.f, 0.f};

        #pragma unroll
        for (int kc = 0; kc < 8; ++kc) {
            const int cur = kc & 1, nxt = cur ^ 1;
            const int nkc = (kc + 1) & 7;
            const int nnt = (kc == 7) ? ((nt + 1) & 7) : nt;
            #pragma unroll
            for (int ni = 0; ni < 2; ++ni) {
                const size_t o = (size_t)nnt * 32768 + (size_t)ni * 4096 + (size_t)nkc * 512;
                Bh[nxt][ni] = *(const bf16x8*)(ehw + o);
                Bl[nxt][ni] = *(const bf16x8*)(elw + o);
            }
            bf16x8 ah[4], al[4];
            #pragma unroll
            for (int mi = 0; mi < 4; ++mi) {
                const int chunk = (kc * 4 + quad) ^ (lr & 7);
                const int o = (mi * 16 + lr) * 256 + chunk * 8;
                ah[mi] = *(const bf16x8*)&zh[o];
                al[mi] = *(const bf16x8*)&zl[o];
            }
            #pragma unroll
            for (int mi = 0; mi < 4; ++mi)
                #pragma unroll
                for (int ni = 0; ni < 2; ++ni) {
                    acc[mi][ni] = __builtin_amdgcn_mfma_f32_16x16x32_bf16(ah[mi], Bh[cur][ni], acc[mi][ni], 0, 0, 0);
                    acc[mi][ni] = __builtin_amdgcn_mfma_f32_16x16x32_bf16(ah[mi], Bl[cur][ni], acc[mi][ni], 0, 0, 0);
                    acc[mi][ni] = __builtin_amdgcn_mfma_f32_16x16x32_bf16(al[mi], Bh[cur][ni], acc[mi][ni], 0, 0, 0);
                }
        }
        const int q0 = nt * 8 + w * 2;
        const float e0b = esq[q0 * 16 + lr] + 512.0f;
        const float e1b = esq[(q0 + 1) * 16 + lr] + 512.0f;
        #pragma unroll
        for (int mi = 0; mi < 4; ++mi)
            #pragma unroll
            for (int reg = 0; reg < 4; ++reg) {
                const int i = mi * 4 + reg;
                #pragma unroll
                for (int ni = 0; ni < 2; ++ni) {
                    const float val = fmaf(-2.0f, acc[mi][ni][reg], ni ? e1b : e0b);
                    const unsigned pk = (__float_as_uint(val) & 0xFFFFFFC0u) | (unsigned)(q0 + ni);
                    const unsigned mx = umax32(bb[i], pk);
                    bb[i] = umin32(bb[i], pk);
                    ss[i] = umin32(ss[i], mx);
                }
            }
    }

    #pragma unroll
    for (int mi = 0; mi < 4; ++mi)
        #pragma unroll
        for (int reg = 0; reg < 4; ++reg) {
            const int i = mi * 4 + reg;
            ull b2 = ((ull)(bb[i] & 0xFFFFFFC0u) << 14) | (ull)((bb[i] & 63u) * 16 + lr);
            ull s2 = ((ull)(ss[i] & 0xFFFFFFC0u) << 14) | (ull)((ss[i] & 63u) * 16 + lr);
            #pragma unroll
            for (int d = 1; d < 16; d <<= 1) {
                const ull ob = __shfl_xor(b2, d);
                const ull os = __shfl_xor(s2, d);
                const ull mx = ob < b2 ? b2 : ob;
                b2 = ob < b2 ? ob : b2;
                const ull ns = os < s2 ? os : s2;
                s2 = mx < ns ? mx : ns;
            }
            if (lr == 0) {
                const int row = mi * 16 + quad * 4 + reg;
                mb[w][row] = b2;
                ms[w][row] = s2;
            }
        }
    __syncthreads();

    if (t < 64) {
        ull b2 = mb[0][t], s2 = ms[0][t];
        #pragma unroll
        for (int ww = 1; ww < 4; ++ww) {
            const ull ob = mb[ww][t], os = ms[ww][t];
            const ull mx = ob < b2 ? b2 : ob;
            b2 = ob < b2 ? ob : b2;
            const ull ns = os < s2 ? os : s2;
            s2 = mx < ns ? mx : ns;
        }
        const int k = (int)(b2 & 16383ull);
        const float v1 = __uint_as_float((unsigned)(b2 >> 14)) - 512.0f;
        const float v2 = __uint_as_float((unsigned)(s2 >> 14)) - 512.0f;
        idx_i[m0 + t] = k;
        idx_f[m0 + t] = (float)k;
        atomicAdd(&hist[k], 1);
        if (v2 - v1 < EPSGAP) {
            const int pos = atomicAdd(flagcnt, 1);
            flaglist[pos] = m0 + t;
            flagval[pos] = v1;
        }
        float lp = v1 + zsqp[t * 4] + zsqp[t * 4 + 1] + zsqp[t * 4 + 2] + zsqp[t * 4 + 3];
        #pragma unroll
        for (int d = 32; d > 0; d >>= 1) lp += __shfl_down(lp, d);
        if (t == 0) loss_p[blockIdx.x] = lp;
    }
}

// ---------------------------------------------------------------------------
// Kernel 4: exact fp32 re-argmin for flagged points; patches idx/hist/loss.
__global__ __launch_bounds__(256) void fixup_kernel(
        const float* __restrict__ zf, const float* __restrict__ emb,
        const float* __restrict__ esq, const int* __restrict__ flagcnt,
        const int* __restrict__ flaglist, const float* __restrict__ flagval,
        int* __restrict__ idx_i, float* __restrict__ idx_f,
        int* __restrict__ hist, float* __restrict__ loss_fix) {
    __shared__ float zrow[256];
    __shared__ ull red[256];
    const int t = threadIdx.x;
    const int total = flagcnt[0];
    for (int fi = blockIdx.x; fi < total; fi += 512) {
        const int n = flaglist[fi];
        __syncthreads();
        zrow[t] = zf[(size_t)n * Dd + t];
        __syncthreads();
        ull best = ~0ull;
        #pragma unroll
        for (int kc = 0; kc < 4; ++kc) {
            const int k = t * 4 + kc;
            const float* ep = emb + (size_t)k * Dd;
            float dot = 0.0f;
            #pragma unroll 8
            for (int c4 = 0; c4 < 64; ++c4) {
                const float4 e4 = *(const float4*)(ep + c4 * 4);
                const float4 z4 = *(const float4*)&zrow[c4 * 4];
                dot = fmaf(z4.x, e4.x, dot);
                dot = fmaf(z4.y, e4.y, dot);
                dot = fmaf(z4.z, e4.z, dot);
                dot = fmaf(z4.w, e4.w, dot);
            }
            const float val = esq[k] - 2.0f * dot;
            const ull pk = ((ull)mono(__float_as_uint(val)) << 32) | (unsigned)k;
            if (pk < best) best = pk;
        }
        red[t] = best;
        __syncthreads();
        for (int s = 128; s > 0; s >>= 1) {
            if (t < s) { if (red[t + s] < red[t]) red[t] = red[t + s]; }
            __syncthreads();
        }
        if (t == 0) {
            const int knew = (int)(unsigned)(red[0] & 0xFFFFFFFFull);
            const float vnew = unmono((unsigned)(red[0] >> 32));
            const int kold = idx_i[n];
            if (knew != kold) {
                idx_i[n] = knew;
                idx_f[n] = (float)knew;
                atomicSub(&hist[kold], 1);
                atomicAdd(&hist[knew], 1);
            }
            atomicAdd(loss_fix, vnew - flagval[fi]);
        }
    }
}

// ---------------------------------------------------------------------------
// Kernel 5: exclusive scan of hist -> offsets, cursor. 1 block.
__global__ void scan_kernel(const int* __restrict__ hist,
                            int* __restrict__ offsets,
                            int* __restrict__ cursor) {
    __shared__ int scan[1024];
    const int t = threadIdx.x;
    const int v = hist[t];
    scan[t] = v;
    __syncthreads();
    for (int s = 1; s < 1024; s <<= 1) {
        const int add = (t >= s) ? scan[t - s] : 0;
        __syncthreads();
        scan[t] += add;
        __syncthreads();
    }
    const int excl = scan[t] - v;
    offsets[t] = excl;
    cursor[t] = excl;
}

// ---------------------------------------------------------------------------
// Kernel 6: counting-sort scatter.
__global__ __launch_bounds__(256) void sort_kernel(
        const int* __restrict__ idx, int* __restrict__ cursor,
        int* __restrict__ sorted, int* __restrict__ codes_sorted) {
    const int n = blockIdx.x * 256 + threadIdx.x;
    const int j = idx[n];
    const int pos = atomicAdd(&cursor[j], 1);
    sorted[pos] = n;
    codes_sorted[pos] = j;
}

// ---------------------------------------------------------------------------
// Kernel 7: balanced segmented reduction -> dw (atomic per segment boundary).
__global__ __launch_bounds__(256) void dw_seg_kernel(
        const float* __restrict__ zf, const int* __restrict__ sorted,
        const int* __restrict__ codes_sorted, float* __restrict__ dw) {
    __shared__ int sid[64];
    __shared__ int scode[65];
    const int t = threadIdx.x;
    const int p0 = blockIdx.x * 64;
    if (t < 64) {
        sid[t] = sorted[p0 + t];
        scode[t] = codes_sorted[p0 + t];
    }
    if (t == 64) scode[64] = -1;
    __syncthreads();
    const int c = t;
    float acc = 0.0f;
    #pragma unroll 8
    for (int p = 0; p < 64; ++p) {
        acc += zf[(size_t)sid[p] * Dd + c];
        if (scode[p] != scode[p + 1]) {
            atomicAdd(&dw[(size_t)scode[p] * Dd + c], acc);
            acc = 0.0f;
        }
    }
}

// ---------------------------------------------------------------------------
// Kernel 8: gather z_q (overwrites zf region; runs after fixup/dw_seg).
__global__ __launch_bounds__(256) void gather_kernel(
        const float* __restrict__ emb, const int* __restrict__ idx,
        float* __restrict__ zq_out) {
    const int tid = blockIdx.x * 256 + threadIdx.x;
    const int e0 = tid * 4;
    const int c = (e0 >> 10) & 255;
    const int b = e0 >> 18;
    const int n0 = b * 1024 + (e0 & 1023);
    const int4 j4 = *(const int4*)(idx + n0);
    float4 e;
    e.x = emb[(size_t)j4.x * Dd + c];
    e.y = emb[(size_t)j4.y * Dd + c];
    e.z = emb[(size_t)j4.z * Dd + c];
    e.w = emb[(size_t)j4.w * Dd + c];
    *(float4*)(zq_out + e0) = e;
}

// ---------------------------------------------------------------------------
// Kernel 9: cluster-size EMA + Laplace smoothing + loss reduce. 1 block.
__global__ void finalize1_kernel(const float* __restrict__ ema_cs,
                                 const int* __restrict__ hist,
                                 const float* __restrict__ loss_p,
                                 const float* __restrict__ loss_fix,
                                 float* __restrict__ cs_out,
                                 float* __restrict__ loss_out) {
    __shared__ float red[1024];
    __shared__ float red2[1024];
    const int k = threadIdx.x;
    const float csr = ema_cs[k] * DECAY + (1.0f - DECAY) * (float)hist[k];
    red[k] = csr;
    red2[k] = (k < 512) ? loss_p[k] : 0.0f;
    __syncthreads();
    for (int s = 512; s > 0; s >>= 1) {
        if (k < s) { red[k] += red[k + s]; red2[k] += red2[k + s]; }
        __syncthreads();
    }
    const float nsum = red[0];
    const float cs = (csr + EPSV) / (nsum + (float)Kk * EPSV) * nsum;
    cs_out[k] = cs;
    if (k == 0) loss_out[0] = BETA * (red2[0] + loss_fix[0]) / (float)ZELEM;
}

// ---------------------------------------------------------------------------
// Kernel 10: new_ema_w = EMA(ema_w, dw); new_emb = new_ema_w / cs.
// dw aliases new_emb_out; each thread reads dw[i] then overwrites same i.
__global__ __launch_bounds__(256) void finalize2_kernel(
        const float* __restrict__ ema_w, const float* __restrict__ dw,
        const float* __restrict__ cs_out,
        float* __restrict__ new_emb_out, float* __restrict__ new_ema_w_out) {
    const int i = blockIdx.x * 256 + threadIdx.x;
    const float nw = ema_w[i] * DECAY + (1.0f - DECAY) * dw[i];
    const float cs = cs_out[i >> 8];
    new_ema_w_out[i] = nw;
    new_emb_out[i]   = nw / cs;
}

// ---------------------------------------------------------------------------
extern "C" void kernel_launch(void* const* d_in, const int* in_sizes, int n_in,
                              void* d_out, int out_size, void* d_ws, size_t ws_size,
                              hipStream_t stream) {
    const float* z      = (const float*)d_in[0];
    const float* emb    = (const float*)d_in[1];
    const float* ema_cs = (const float*)d_in[2];
    const float* ema_w  = (const float*)d_in[3];

    float* out = (float*)d_out;
    float* zq_out        = out;                 // 8388608 (zf staging until gather)
    float* idx_out_f     = out + 8388608;       // 32768
    float* loss_out      = out + 8421376;       // 1
    float* new_emb_out   = out + 8421377;       // 262144 (dw staging)
    float* cs_out        = out + 8683521;       // 1024
    float* new_ema_w_out = out + 8684545;       // 262144

    int*   idx_i    = (int*)d_ws;                    // 32768
    int*   sorted   = idx_i + 32768;                 // 32768
    int*   codes_s  = sorted + 32768;                // 32768
    int*   offsets  = codes_s + 32768;               // 1024
    int*   cursor   = offsets + 1024;                // 1024
    int*   hist     = cursor + 1024;                 // 1024
    int*   flagcnt  = hist + 1024;                   // 16
    float* loss_fix = (float*)(flagcnt + 16);        // 16
    int*   flaglist = (int*)(loss_fix + 16);         // 32768
    float* flagval  = (float*)(flaglist + 32768);    // 32768
    float* esq      = flagval + 32768;               // 1024
    float* loss_p   = esq + 1024;                    // 512
    unsigned short* ehg = (unsigned short*)(loss_p + 512);  // 262144 shorts
    unsigned short* elg = ehg + 262144;                     // 262144 shorts

    float* zf = zq_out;        // transposed z staged in zq output region
    float* dw = new_emb_out;   // dw staged in new_embedding output region

    prep_e_kernel<<<64, 256, 0, stream>>>(emb, ehg, elg, esq, hist, flagcnt,
                                          loss_fix, dw);
    transpose_kernel<<<2048, 256, 0, stream>>>(z, zf);
    dist_kernel<<<Nn / 64, 256, 0, stream>>>(z, ehg, elg, esq, idx_i,
                                             idx_out_f, hist, flagcnt,
                                             flaglist, flagval, loss_p);
    fixup_kernel<<<512, 256, 0, stream>>>(zf, emb, esq, flagcnt, flaglist,
                                          flagval, idx_i, idx_out_f, hist,
                                          loss_fix);
    scan_kernel<<<1, 1024, 0, stream>>>(hist, offsets, cursor);
    sort_kernel<<<Nn / 256, 256, 0, stream>>>(idx_i, cursor, sorted, codes_s);
    dw_seg_kernel<<<Nn / 64, 256, 0, stream>>>(zf, sorted, codes_s, dw);
    gather_kernel<<<ZELEM / 1024, 256, 0, stream>>>(emb, idx_i, zq_out);
    finalize1_kernel<<<1, 1024, 0, stream>>>(ema_cs, hist, loss_p, loss_fix,
                                             cs_out, loss_out);
    finalize2_kernel<<<Kk * Dd / 256, 256, 0, stream>>>(ema_w, dw, cs_out,
                                                        new_emb_out, new_ema_w_out);
}